// Round 5
// baseline (609.900 us; speedup 1.0000x reference)
//
#include <hip/hip_runtime.h>
#include <hip/hip_cooperative_groups.h>

// EMA scan: a_t = w*x_t + (1-w)*a_{t-1}, y_t = a_t
// x: [B,T,F] fp32, initial_state: [B,F] fp32, smooth: [1] fp32 (clipped to [0,1])
//
// Single fused cooperative kernel:
//   step A: per-chunk local scan from zero -> chunk-final P_c (warms L3 with x)
//   grid.sync()
//   step B: exact carry-in via Horner over predecessor chunk-finals
//   step C: re-scan own chunk (L3-hot) seeded with carry-in, nt-write y
//
// ROUND-4 LESSON (VGPR_Count=32, 1.86 TB/s, VALUBusy 2.6%): the compiler
// emitted load->vmcnt(0)->FMA per step — ~1 outstanding load/wave —
// latency-bound at exactly 1KB*16waves/900cyc. Fix: explicit 8-deep load
// batches (f4v buf[8], fully static-indexed) with #pragma unroll 1 on the
// outer loop so 8 independent 16B loads are in flight before the serial
// FMA chain consumes them. Same pattern in step C; batch-4 in step B.
#define B_   16
#define T_   8192
#define F_   512
#define F4_  (F_ / 4)       // 128 float4 per (b,t) row
#define BF4_ (B_ * F4_)     // 2048 columns (b,f4)
#define C_   128            // chunks along T
#define LC_  7              // log2(C_)
#define L_   (T_ / C_)      // 64 timesteps per chunk

typedef float f4v __attribute__((ext_vector_type(4)));

__device__ f4v g_carry[C_ * BF4_];   // 4 MiB static carry buffer

namespace cg = cooperative_groups;

__global__ __launch_bounds__(256, 4) void ema_fused(const float* __restrict__ x,
                                                    const float* __restrict__ init,
                                                    const float* __restrict__ smooth,
                                                    float* __restrict__ y) {
    const int tid = blockIdx.x * blockDim.x + threadIdx.x;   // 0 .. B_*C_*F4_-1
    const int f4  = tid & (F4_ - 1);
    const int m   = tid >> 7;              // row-chunk index, wave-uniform
    const int c   = m & (C_ - 1);
    const int b   = m >> LC_;
    float w = smooth[0];
    w = fminf(fmaxf(w, 0.0f), 1.0f);
    const float d = 1.0f - w;

    const size_t base = (size_t)(b * T_ + c * L_) * F4_ + f4;
    const f4v*   xp   = reinterpret_cast<const f4v*>(x) + base;
    const int    col  = b * F4_ + f4;

    // ---- Step A: local scan from zero; publish chunk-final P_c ----
    f4v a = {0.f, 0.f, 0.f, 0.f};
#pragma unroll 1
    for (int s0 = 0; s0 < L_; s0 += 8) {
        f4v buf[8];
#pragma unroll
        for (int u = 0; u < 8; ++u)
            buf[u] = xp[(size_t)(s0 + u) * F4_];
#pragma unroll
        for (int u = 0; u < 8; ++u) {
            a.x = fmaf(d, a.x, w * buf[u].x);
            a.y = fmaf(d, a.y, w * buf[u].y);
            a.z = fmaf(d, a.z, w * buf[u].z);
            a.w = fmaf(d, a.w, w * buf[u].w);
        }
    }
    g_carry[(size_t)c * BF4_ + col] = a;

    cg::this_grid().sync();

    // ---- Step B: exact carry-in by Horner over predecessor chunk-finals ----
    // A_c = dL^c * A0 + sum_{j<c} dL^{c-1-j} P_j, evaluated oldest-first.
    const float dL = powf(d, (float)L_);
    f4v A = reinterpret_cast<const f4v*>(init)[col];
    int j = 0;
#pragma unroll 1
    for (; j + 4 <= c; j += 4) {
        f4v p0 = g_carry[(size_t)(j + 0) * BF4_ + col];
        f4v p1 = g_carry[(size_t)(j + 1) * BF4_ + col];
        f4v p2 = g_carry[(size_t)(j + 2) * BF4_ + col];
        f4v p3 = g_carry[(size_t)(j + 3) * BF4_ + col];
        A.x = fmaf(dL, A.x, p0.x); A.y = fmaf(dL, A.y, p0.y);
        A.z = fmaf(dL, A.z, p0.z); A.w = fmaf(dL, A.w, p0.w);
        A.x = fmaf(dL, A.x, p1.x); A.y = fmaf(dL, A.y, p1.y);
        A.z = fmaf(dL, A.z, p1.z); A.w = fmaf(dL, A.w, p1.w);
        A.x = fmaf(dL, A.x, p2.x); A.y = fmaf(dL, A.y, p2.y);
        A.z = fmaf(dL, A.z, p2.z); A.w = fmaf(dL, A.w, p2.w);
        A.x = fmaf(dL, A.x, p3.x); A.y = fmaf(dL, A.y, p3.y);
        A.z = fmaf(dL, A.z, p3.z); A.w = fmaf(dL, A.w, p3.w);
    }
#pragma unroll 1
    for (; j < c; ++j) {
        f4v p = g_carry[(size_t)j * BF4_ + col];
        A.x = fmaf(dL, A.x, p.x); A.y = fmaf(dL, A.y, p.y);
        A.z = fmaf(dL, A.z, p.z); A.w = fmaf(dL, A.w, p.w);
    }

    // ---- Step C: re-scan own chunk seeded with A_c; write y ----
    // x was read by step A and (256 MiB = L3 size) is still L3-resident;
    // nt loads (last use) and nt stores (never re-read) avoid evicting it.
    f4v* yp = reinterpret_cast<f4v*>(y) + base;
#pragma unroll 1
    for (int s0 = 0; s0 < L_; s0 += 8) {
        f4v buf[8];
#pragma unroll
        for (int u = 0; u < 8; ++u)
            buf[u] = __builtin_nontemporal_load(&xp[(size_t)(s0 + u) * F4_]);
#pragma unroll
        for (int u = 0; u < 8; ++u) {
            A.x = fmaf(d, A.x, w * buf[u].x);
            A.y = fmaf(d, A.y, w * buf[u].y);
            A.z = fmaf(d, A.z, w * buf[u].z);
            A.w = fmaf(d, A.w, w * buf[u].w);
            __builtin_nontemporal_store(A, &yp[(size_t)(s0 + u) * F4_]);
        }
    }
}

extern "C" void kernel_launch(void* const* d_in, const int* in_sizes, int n_in,
                              void* d_out, int out_size, void* d_ws, size_t ws_size,
                              hipStream_t stream) {
    const float* x      = (const float*)d_in[0];
    const float* init   = (const float*)d_in[1];
    const float* smooth = (const float*)d_in[2];
    float*       y      = (float*)d_out;
    (void)d_ws; (void)ws_size;   // workspace unused (carry is static __device__)

    void* args[] = { (void*)&x, (void*)&init, (void*)&smooth, (void*)&y };
    const int grid = (B_ * C_ * F4_) / 256;   // 1024 blocks, 4/CU — co-resident
    hipLaunchCooperativeKernel((const void*)ema_fused, dim3(grid), dim3(256),
                               args, 0, stream);
}

// Round 6
// 490.844 us; speedup vs baseline: 1.2426x; 1.2426x over previous
//
#include <hip/hip_runtime.h>

// EMA scan: a_t = w*x_t + (1-w)*a_{t-1}, y_t = a_t
// x: [B,T,F] fp32, initial_state: [B,F] fp32, smooth: [1] fp32 (clipped to [0,1])
//
// TWO-dispatch exact chunked scan (reverted from fused-coop: measured 300 us
// vs trio's ~177 us for identical HBM traffic; coop/grid-sync structure was
// the regression, mechanism unattributed):
//   kernel 1: per-chunk local scan from zero -> chunk-final P_c into static
//             carry (normal caching loads warm the 256 MiB L3 with x).
//   kernel 2: per-thread Horner over predecessor chunk-finals gives the exact
//             carry-in A_c = dL^c*A0 + sum_{j<c} dL^{c-1-j} P_j  (replaces the
//             old separate Kogge-Stone dispatch), then rescan own chunk and
//             nt-store y. REVERSED traversal: first-scheduled blocks have the
//             longest Horner chains (hidden under others' streaming) and
//             consume the most-recently-cached tail of x.
// Phase-3 x loads are NORMAL this round (deliberate A/B vs round-3's nt
// loads: nt-load has no help-mechanism — x is already L3-resident — and TCC
// counters cannot see whether nt bypasses L3). y stores stay non-temporal
// (never re-read; keeps y from evicting x).
// Carry lives in a 4 MiB static __device__ array (benched clean r4/r5); the
// harness's 1 GiB ws-poison fill is unconditional (~309 us fixed overhead
// incl. other resets), so d_ws usage is irrelevant — we leave it untouched.
#define B_   16
#define T_   8192
#define F_   512
#define F4_  (F_ / 4)       // 128 float4 per (b,t) row
#define BF4_ (B_ * F4_)     // 2048 columns (b,f4)
#define C_   128            // chunks along T
#define LC_  7              // log2(C_)
#define L_   (T_ / C_)      // 64 timesteps per chunk

typedef float f4v __attribute__((ext_vector_type(4)));

__device__ f4v g_carry[C_ * BF4_];   // 4 MiB static carry buffer

__device__ __forceinline__ float read_w(const float* smooth) {
    float w = smooth[0];
    return fminf(fmaxf(w, 0.0f), 1.0f);
}

// ---- Kernel 1: per-chunk local scan from zero; publish chunk-final P_c ----
__global__ __launch_bounds__(256, 4) void ema_phase1(const float* __restrict__ x,
                                                     const float* __restrict__ smooth) {
    const int tid = blockIdx.x * blockDim.x + threadIdx.x;   // 0 .. B_*C_*F4_-1
    const int f4  = tid & (F4_ - 1);
    const int c   = (tid >> 7) & (C_ - 1);
    const int b   = tid >> (7 + LC_);
    const float w = read_w(smooth);
    const float d = 1.0f - w;

    const f4v* xp = reinterpret_cast<const f4v*>(x)
                  + (size_t)(b * T_ + c * L_) * F4_ + f4;
    f4v a = {0.f, 0.f, 0.f, 0.f};
#pragma unroll 8
    for (int s = 0; s < L_; ++s) {
        f4v xv = xp[(size_t)s * F4_];
        a.x = fmaf(d, a.x, w * xv.x);
        a.y = fmaf(d, a.y, w * xv.y);
        a.z = fmaf(d, a.z, w * xv.z);
        a.w = fmaf(d, a.w, w * xv.w);
    }
    g_carry[(size_t)c * BF4_ + b * F4_ + f4] = a;
}

// ---- Kernel 2: Horner carry-in + rescan own chunk + nt-store y ----
__global__ __launch_bounds__(256, 4) void ema_carry_scan(const float* __restrict__ x,
                                                         const float* __restrict__ init,
                                                         const float* __restrict__ smooth,
                                                         float* __restrict__ y) {
    const int tid = blockIdx.x * blockDim.x + threadIdx.x;
    const int f4  = tid & (F4_ - 1);
    const int m   = (B_ * C_ - 1) - (tid >> 7);   // reversed row-chunk index
    const int c   = m & (C_ - 1);
    const int b   = m >> LC_;
    const float w = read_w(smooth);
    const float d = 1.0f - w;
    const float dL = powf(d, (float)L_);
    const int col = b * F4_ + f4;

    // Exact carry-in by Horner over predecessor chunk-finals (oldest-first):
    // A_c = dL^c * A0 + sum_{j<c} dL^{c-1-j} P_j.  Batched x4 for L2 MLP.
    f4v A = reinterpret_cast<const f4v*>(init)[col];
    int j = 0;
#pragma unroll 1
    for (; j + 4 <= c; j += 4) {
        f4v p0 = g_carry[(size_t)(j + 0) * BF4_ + col];
        f4v p1 = g_carry[(size_t)(j + 1) * BF4_ + col];
        f4v p2 = g_carry[(size_t)(j + 2) * BF4_ + col];
        f4v p3 = g_carry[(size_t)(j + 3) * BF4_ + col];
        A.x = fmaf(dL, A.x, p0.x); A.y = fmaf(dL, A.y, p0.y);
        A.z = fmaf(dL, A.z, p0.z); A.w = fmaf(dL, A.w, p0.w);
        A.x = fmaf(dL, A.x, p1.x); A.y = fmaf(dL, A.y, p1.y);
        A.z = fmaf(dL, A.z, p1.z); A.w = fmaf(dL, A.w, p1.w);
        A.x = fmaf(dL, A.x, p2.x); A.y = fmaf(dL, A.y, p2.y);
        A.z = fmaf(dL, A.z, p2.z); A.w = fmaf(dL, A.w, p2.w);
        A.x = fmaf(dL, A.x, p3.x); A.y = fmaf(dL, A.y, p3.y);
        A.z = fmaf(dL, A.z, p3.z); A.w = fmaf(dL, A.w, p3.w);
    }
#pragma unroll 1
    for (; j < c; ++j) {
        f4v p = g_carry[(size_t)j * BF4_ + col];
        A.x = fmaf(dL, A.x, p.x); A.y = fmaf(dL, A.y, p.y);
        A.z = fmaf(dL, A.z, p.z); A.w = fmaf(dL, A.w, p.w);
    }

    // Rescan own chunk seeded with A_c; x via NORMAL loads (L3-hot from
    // kernel 1), y via non-temporal stores (never re-read; protect x in L3).
    const size_t base = (size_t)(b * T_ + c * L_) * F4_ + f4;
    const f4v* xp = reinterpret_cast<const f4v*>(x) + base;
    f4v*       yp = reinterpret_cast<f4v*>(y) + base;
#pragma unroll 8
    for (int s = 0; s < L_; ++s) {
        f4v xv = xp[(size_t)s * F4_];
        A.x = fmaf(d, A.x, w * xv.x);
        A.y = fmaf(d, A.y, w * xv.y);
        A.z = fmaf(d, A.z, w * xv.z);
        A.w = fmaf(d, A.w, w * xv.w);
        __builtin_nontemporal_store(A, &yp[(size_t)s * F4_]);
    }
}

extern "C" void kernel_launch(void* const* d_in, const int* in_sizes, int n_in,
                              void* d_out, int out_size, void* d_ws, size_t ws_size,
                              hipStream_t stream) {
    const float* x      = (const float*)d_in[0];
    const float* init   = (const float*)d_in[1];
    const float* smooth = (const float*)d_in[2];
    float*       y      = (float*)d_out;
    (void)d_ws; (void)ws_size;   // workspace unused (carry is static __device__)

    const int grid = (B_ * C_ * F4_) / 256;   // 1024 blocks, 4/CU
    ema_phase1<<<grid, 256, 0, stream>>>(x, smooth);
    ema_carry_scan<<<grid, 256, 0, stream>>>(x, init, smooth, y);
}